// Round 15
// baseline (190.671 us; speedup 1.0000x reference)
//
#include <hip/hip_runtime.h>
#include <cstdint>
#include <cstddef>

typedef __bf16 bf16;
typedef __bf16 bf16x8 __attribute__((ext_vector_type(8)));
typedef float  f32x4  __attribute__((ext_vector_type(4)));

#define NB 4
#define SS 2048
#define EE 1024

// kloop32w buffer: A-tile 128x32 bf16 (8 KB) + B-tile 256x32 (16 KB)
#define BUFB   24576
#define LDS3   (3 * BUFB)     // 73728 B -> 2 blocks/CU (scores)
// kloop32a buffer: A-tile 128x32 FP32 (16 KB) + B-tile 256x32 bf16 (16 KB)
#define BUFA32 32768
#define LDSA3  (3 * BUFA32)   // 98304 B -> 1 block/CU (proj)
// kloop64 buffer: A-tile 128x64 (16 KB) + B-tile 256x64 (32 KB)
#define BUFB64 49152
#define LDS64  (3 * BUFB64)   // 147456 B -> 1 block/CU (pv)
#define LDS64P (LDS64 + 512)  // + invs[128] row-scale table (pv)

// ---------------------------------------------------------------------------
// Async global->LDS, 16 B/lane. LDS dest = wave-uniform base + lane*16
// (m104/m108); global src is per-lane (swizzle applied on the src side).
// ---------------------------------------------------------------------------
static __device__ __forceinline__ void glds16(const void* g, void* l)
{
    __builtin_amdgcn_global_load_lds(
        (const __attribute__((address_space(1))) unsigned int*)g,
        (__attribute__((address_space(3))) unsigned int*)l,
        16, 0, 0);
}

// Bijective XCD-aware swizzle (all grids here have nwg % 8 == 0).
static __device__ __forceinline__ void swz_block(int& bx, int& by, int& bz)
{
    const int nx = gridDim.x, ny = gridDim.y;
    const int nwg = nx * ny * gridDim.z;
    int lin = blockIdx.x + nx * (blockIdx.y + ny * blockIdx.z);
    const int per = nwg >> 3;
    lin = (lin & 7) * per + (lin >> 3);
    bz = lin / (nx * ny);
    const int r = lin - bz * nx * ny;
    by = r / nx;
    bx = r - by * nx;
}

// ---------------------------------------------------------------------------
// kloop32a [r15]: kloop32 skeleton with A staged as RAW FP32 via glds16
// (kills the q/k/v cvt pre-pass; no reg round-trip -> no r10-style drain).
// BK=32, BM=128, BN=256, 512 thr = 8 waves (2M x 4N), per-wave 64x64.
// A: fp32 [128][32], 128-B rows, 8 chunks, swizzle chunk ^= row&7 (kloop64's
// proven involution; frag reads conflict-free). Frag read = 2x ds_read_b128
// f32 + 8 cvt to bf16x8 (~32 VALU/tile, negligible vs 310cyc MFMA).
// B: bf16 [256][32] identical to kloop32 (chunk ^= (row>>1)&3).
// NBUF=3 (96 KB -> 1 blk/CU), depth-2 prefetch, 4 vmem/tile -> boundary
// vmcnt(4) (T4: never drain in-loop), dummy-tail restage.
// ---------------------------------------------------------------------------
static __device__ __forceinline__ void kloop32a(
    const float* __restrict__ A, const bf16* __restrict__ Bm,
    int lda, int ldb, int nt, char* lds, int m0, int n0, int tid,
    f32x4 acc[4][4])
{
    constexpr int NBUF = 3;
    const int lane = tid & 63, w = tid >> 6;
    const int wm = w >> 2, wn = w & 3;
    const int lr = lane & 15, kq = lane >> 4;
    const int cbB = ((kq ^ ((lr >> 1) & 3)) << 4);        // B col byte (64-B rows)
    const int ca0 = (((2 * kq)     ^ (lr & 7)) << 4);     // A chunk bytes (128-B rows)
    const int ca1 = (((2 * kq + 1) ^ (lr & 7)) << 4);

    // A staging: thread -> (row tid>>3 in 0..63, phys chunk tid&7); 2 issues.
    const int arow = tid >> 3;
    const int achk = (tid & 7) ^ (arow & 7);              // inverse-swizzled src
    const float* Asrc = A + (size_t)(m0 + arow) * lda + achk * 4;
    // B staging identical to kloop32: thread -> (row tid>>2, chunk tid&3).
    const int brow = tid >> 2;
    const int bchk = (tid & 3) ^ ((brow >> 1) & 3);
    const bf16* Bsrc = Bm + (size_t)(n0 + brow) * ldb + bchk * 8;
    const int wofs = w << 10;

#pragma unroll
    for (int p = 0; p < NBUF - 1; ++p) {
        char* d = lds + p * BUFA32;
        const int kt = p * 32;
        glds16(Asrc + kt,                     d + wofs);
        glds16(Asrc + (size_t)64 * lda + kt,  d + 8192 + wofs);
        glds16(Bsrc + kt,                     d + 16384 + wofs);
        glds16(Bsrc + (size_t)128 * ldb + kt, d + 24576 + wofs);
    }
    asm volatile("s_waitcnt vmcnt(4)" ::: "memory");
    __builtin_amdgcn_sched_barrier(0);
    __builtin_amdgcn_s_barrier();
    __builtin_amdgcn_sched_barrier(0);

    int rb = 0, sb = NBUF - 1;
    for (int t = 0; t < nt; ++t) {
        char* la = lds + rb * BUFA32;
        char* lb = la + 16384;
        const int ts = (t + NBUF - 1 < nt) ? t + NBUF - 1 : nt - 1; // dummy tail
        const int kt = ts * 32;
        char* d = lds + sb * BUFA32;

        bf16x8 af[4], bg[4];
#pragma unroll
        for (int m = 0; m < 4; ++m) {
            const int r = wm * 64 + m * 16 + lr;
            const f32x4 a0 = *(const f32x4*)(la + r * 128 + ca0);
            const f32x4 a1 = *(const f32x4*)(la + r * 128 + ca1);
            bf16x8 tf;
            tf[0] = (bf16)a0[0]; tf[1] = (bf16)a0[1]; tf[2] = (bf16)a0[2]; tf[3] = (bf16)a0[3];
            tf[4] = (bf16)a1[0]; tf[5] = (bf16)a1[1]; tf[6] = (bf16)a1[2]; tf[7] = (bf16)a1[3];
            af[m] = tf;
        }
#pragma unroll
        for (int n = 0; n < 4; ++n)
            bg[n] = *(const bf16x8*)(lb + (wn * 64 + n * 16 + lr) * 64 + cbB);

        glds16(Asrc + kt,                     d + wofs);
        glds16(Asrc + (size_t)64 * lda + kt,  d + 8192 + wofs);
        glds16(Bsrc + kt,                     d + 16384 + wofs);
        glds16(Bsrc + (size_t)128 * ldb + kt, d + 24576 + wofs);

        __builtin_amdgcn_s_setprio(1);
#pragma unroll
        for (int m = 0; m < 4; ++m)
#pragma unroll
            for (int n = 0; n < 4; ++n)
                acc[m][n] = __builtin_amdgcn_mfma_f32_16x16x32_bf16(af[m], bg[n], acc[m][n], 0, 0, 0);
        __builtin_amdgcn_s_setprio(0);

        if (t < nt - 1) {
            asm volatile("s_waitcnt vmcnt(4)" ::: "memory");
            __builtin_amdgcn_sched_barrier(0);
            __builtin_amdgcn_s_barrier();
            __builtin_amdgcn_sched_barrier(0);
        }
        rb = (rb + 1 == NBUF) ? 0 : rb + 1;
        sb = (sb + 1 == NBUF) ? 0 : sb + 1;
    }
    asm volatile("s_waitcnt vmcnt(0)" ::: "memory");  // drain dummy-tail loads
}

// ---------------------------------------------------------------------------
// kloop32w [r12, measured best for scores]: BK=32, BM=128, BN=256,
// 256 thr = 4 waves (2M x 2N), per-wave 64x128. NBUF=3 / vmcnt(6);
// 6 glds16/tile (4 KB issues). Swizzle chunk ^= (row>>1)&3.
// ---------------------------------------------------------------------------
static __device__ __forceinline__ void kloop32w(
    const bf16* __restrict__ A, const bf16* __restrict__ Bm,
    int lda, int ldb, int nt, char* lds, int m0, int n0, int tid,
    f32x4 acc[4][8])
{
    constexpr int NBUF = 3;
    const int lane = tid & 63, w = tid >> 6;       // w 0..3
    const int wm = w >> 1, wn = w & 1;
    const int lr = lane & 15, kq = lane >> 4;
    const int cb = ((kq ^ ((lr >> 1) & 3)) << 4);

    const int srow   = tid >> 2;                   // 0..63
    const int chunkL = (tid & 3) ^ ((srow >> 1) & 3);
    const bf16* Asrc = A  + (size_t)(m0 + srow) * lda + chunkL * 8;
    const bf16* Bsrc = Bm + (size_t)(n0 + srow) * ldb + chunkL * 8;
    const int wofs = w << 10;                      // wave base within 4 KB issue

#pragma unroll
    for (int p = 0; p < NBUF - 1; ++p) {
        char* d = lds + p * BUFB + wofs;
        const int kt = p * 32;
        glds16(Asrc + kt,                      d);
        glds16(Asrc + (size_t)64  * lda + kt,  d + 4096);
        glds16(Bsrc + kt,                      d + 8192);
        glds16(Bsrc + (size_t)64  * ldb + kt,  d + 12288);
        glds16(Bsrc + (size_t)128 * ldb + kt,  d + 16384);
        glds16(Bsrc + (size_t)192 * ldb + kt,  d + 20480);
    }
    asm volatile("s_waitcnt vmcnt(6)" ::: "memory");
    __builtin_amdgcn_sched_barrier(0);
    __builtin_amdgcn_s_barrier();
    __builtin_amdgcn_sched_barrier(0);

    int rb = 0, sb = NBUF - 1;
    for (int t = 0; t < nt; ++t) {
        char* la = lds + rb * BUFB;
        char* lb = la + 8192;
        const int ts = (t + NBUF - 1 < nt) ? t + NBUF - 1 : nt - 1; // dummy tail
        const int kt = ts * 32;
        char* d = lds + sb * BUFB + wofs;

        bf16x8 af[4], bg[8];
#pragma unroll
        for (int m = 0; m < 4; ++m)
            af[m] = *(const bf16x8*)(la + (wm * 64 + m * 16 + lr) * 64 + cb);
#pragma unroll
        for (int n = 0; n < 8; ++n)
            bg[n] = *(const bf16x8*)(lb + (wn * 128 + n * 16 + lr) * 64 + cb);

        glds16(Asrc + kt,                      d);
        glds16(Asrc + (size_t)64  * lda + kt,  d + 4096);
        glds16(Bsrc + kt,                      d + 8192);
        glds16(Bsrc + (size_t)64  * ldb + kt,  d + 12288);
        glds16(Bsrc + (size_t)128 * ldb + kt,  d + 16384);
        glds16(Bsrc + (size_t)192 * ldb + kt,  d + 20480);

        __builtin_amdgcn_s_setprio(1);
#pragma unroll
        for (int m = 0; m < 4; ++m)
#pragma unroll
            for (int n = 0; n < 8; ++n)
                acc[m][n] = __builtin_amdgcn_mfma_f32_16x16x32_bf16(af[m], bg[n], acc[m][n], 0, 0, 0);
        __builtin_amdgcn_s_setprio(0);

        if (t < nt - 1) {
            asm volatile("s_waitcnt vmcnt(6)" ::: "memory");
            __builtin_amdgcn_sched_barrier(0);
            __builtin_amdgcn_s_barrier();
            __builtin_amdgcn_sched_barrier(0);
        }
        rb = (rb + 1 == NBUF) ? 0 : rb + 1;
        sb = (sb + 1 == NBUF) ? 0 : sb + 1;
    }
    asm volatile("s_waitcnt vmcnt(0)" ::: "memory");  // drain dummy-tail loads
}

// ---------------------------------------------------------------------------
// kloop64 [r3 verbatim; used by pv]: BK=64, BM=128, BN=256, NBUF=3 x 48 KB
// (1 block/CU), depth-2, boundary vmcnt(6), two k-slice phases per tile.
// Swizzle: chunk ^= (row&7) on 128-B rows (measured 0 conflicts).
// ---------------------------------------------------------------------------
static __device__ __forceinline__ void kloop64(
    const bf16* __restrict__ A, const bf16* __restrict__ Bm,
    int lda, int ldb, int nt, char* lds, int m0, int n0, int tid,
    f32x4 acc[4][4])
{
    const int lane = tid & 63, w = tid >> 6;
    const int wm = w >> 2, wn = w & 3;
    const int lr = lane & 15, kq = lane >> 4;
    const int axor = (lr & 7) << 4;

    const int srow   = tid >> 3;
    const int chunkL = (tid & 7) ^ (srow & 7);
    const bf16* Asrc = A  + (size_t)(m0 + srow) * lda + chunkL * 8;
    const bf16* Bsrc = Bm + (size_t)(n0 + srow) * ldb + chunkL * 8;
    const int wofs = w << 10;

#pragma unroll
    for (int p = 0; p < 2; ++p) {
        char* d = lds + p * BUFB64 + wofs;
        const int kt = p * 64;
        glds16(Asrc + kt,                        d);
        glds16(Asrc + (size_t)64 * lda + kt,     d + 8192);
        glds16(Bsrc + kt,                        d + 16384);
        glds16(Bsrc + (size_t)64 * ldb + kt,     d + 16384 + 8192);
        glds16(Bsrc + (size_t)128 * ldb + kt,    d + 16384 + 16384);
        glds16(Bsrc + (size_t)192 * ldb + kt,    d + 16384 + 24576);
    }
    asm volatile("s_waitcnt vmcnt(6)" ::: "memory");
    __builtin_amdgcn_sched_barrier(0);
    __builtin_amdgcn_s_barrier();
    __builtin_amdgcn_sched_barrier(0);

    for (int t = 0; t < nt; ++t) {
        char* la = lds + (t % 3) * BUFB64;
        char* lb = la + 16384;
        char* sa = lds + ((t + 2) % 3) * BUFB64;
        const bool st = (t + 2) < nt;
        const int kt = (t + 2) * 64;

        bf16x8 af[4], bg[4];
        {
            const int cbk = (kq * 16) ^ axor;
#pragma unroll
            for (int m = 0; m < 4; ++m)
                af[m] = *(const bf16x8*)(la + (wm * 64 + m * 16 + lr) * 128 + cbk);
#pragma unroll
            for (int n = 0; n < 4; ++n)
                bg[n] = *(const bf16x8*)(lb + (wn * 64 + n * 16 + lr) * 128 + cbk);
            if (st) {
                glds16(Asrc + kt,                    sa + wofs);
                glds16(Asrc + (size_t)64 * lda + kt, sa + 8192 + wofs);
                glds16(Bsrc + kt,                    sa + 16384 + wofs);
            }
            __builtin_amdgcn_s_setprio(1);
#pragma unroll
            for (int m = 0; m < 4; ++m)
#pragma unroll
                for (int n = 0; n < 4; ++n)
                    acc[m][n] = __builtin_amdgcn_mfma_f32_16x16x32_bf16(af[m], bg[n], acc[m][n], 0, 0, 0);
            __builtin_amdgcn_s_setprio(0);
        }
        {
            const int cbk = (64 + kq * 16) ^ axor;
#pragma unroll
            for (int m = 0; m < 4; ++m)
                af[m] = *(const bf16x8*)(la + (wm * 64 + m * 16 + lr) * 128 + cbk);
#pragma unroll
            for (int n = 0; n < 4; ++n)
                bg[n] = *(const bf16x8*)(lb + (wn * 64 + n * 16 + lr) * 128 + cbk);
            if (st) {
                glds16(Bsrc + (size_t)64 * ldb + kt,  sa + 16384 + 8192 + wofs);
                glds16(Bsrc + (size_t)128 * ldb + kt, sa + 16384 + 16384 + wofs);
                glds16(Bsrc + (size_t)192 * ldb + kt, sa + 16384 + 24576 + wofs);
            }
            __builtin_amdgcn_s_setprio(1);
#pragma unroll
            for (int m = 0; m < 4; ++m)
#pragma unroll
                for (int n = 0; n < 4; ++n)
                    acc[m][n] = __builtin_amdgcn_mfma_f32_16x16x32_bf16(af[m], bg[n], acc[m][n], 0, 0, 0);
            __builtin_amdgcn_s_setprio(0);
        }
        if (t < nt - 1) {
            if (st) { asm volatile("s_waitcnt vmcnt(6)" ::: "memory"); }
            else    { asm volatile("s_waitcnt vmcnt(0)" ::: "memory"); }
            __builtin_amdgcn_sched_barrier(0);
            __builtin_amdgcn_s_barrier();
            __builtin_amdgcn_sched_barrier(0);
        }
    }
}

// ---------------------------------------------------------------------------
// K0: fp32 -> bf16 convert for the three weight matrices only (q/k/v are
// consumed as fp32 directly by proj8's kloop32a).
// ---------------------------------------------------------------------------
__global__ __launch_bounds__(256) void cvt_w(
    const float* __restrict__ Wq, const float* __restrict__ Wk, const float* __restrict__ Wv,
    bf16* __restrict__ Wc)
{
    const int y = blockIdx.y;
    const float* s = (y == 0) ? Wq : (y == 1) ? Wk : Wv;
    bf16* d = Wc + (size_t)y * EE * EE;
    const size_t i = ((size_t)blockIdx.x * 256 + threadIdx.x) * 8;
    const float4 f0 = *(const float4*)(s + i);
    const float4 f1 = *(const float4*)(s + i + 4);
    bf16x8 h;
    h[0] = (bf16)f0.x; h[1] = (bf16)f0.y; h[2] = (bf16)f0.z; h[3] = (bf16)f0.w;
    h[4] = (bf16)f1.x; h[5] = (bf16)f1.y; h[6] = (bf16)f1.z; h[7] = (bf16)f1.w;
    *(bf16x8*)(d + i) = h;
}

// ---------------------------------------------------------------------------
// K1: fused QKV projection [r15 — fp32 A via kloop32a, 512 thr]. M=8192
// (flat b*s), N=K=1024, z selects q/k/v. z<2: [s][e] bf16 write. z==2:
// transposed epilogue via chunk-XOR LDS tile -> vt[b][e][s].
// C/D 16x16 layout: col = lane&15, row = (lane>>4)*4 + j  [m89/m91].
// ---------------------------------------------------------------------------
__global__ __launch_bounds__(512) void proj8(
    const float* __restrict__ query, const float* __restrict__ key_,
    const float* __restrict__ value,
    const bf16* __restrict__ Wc,
    const float* __restrict__ bq, const float* __restrict__ bk, const float* __restrict__ bv,
    bf16* __restrict__ qb, bf16* __restrict__ kb, bf16* __restrict__ vt)
{
    extern __shared__ char lds[];
    int bx, by, bz; swz_block(bx, by, bz);
    const float* A; const float* bias;
    if (bz == 0)      { A = query; bias = bq; }
    else if (bz == 1) { A = key_;  bias = bk; }
    else              { A = value; bias = bv; }
    const bf16* Bm = Wc + (size_t)bz * EE * EE;

    const int m0 = by * 128, n0 = bx * 256;
    const int tid = threadIdx.x;

    f32x4 acc[4][4];
#pragma unroll
    for (int m = 0; m < 4; ++m)
#pragma unroll
        for (int n = 0; n < 4; ++n) { acc[m][n][0] = 0.f; acc[m][n][1] = 0.f; acc[m][n][2] = 0.f; acc[m][n][3] = 0.f; }

    kloop32a(A, Bm, EE, EE, EE / 32, lds, m0, n0, tid, acc);

    const int lane = tid & 63, w = tid >> 6, wm = w >> 2, wn = w & 3;
    const int lr = lane & 15, kq = lane >> 4;

    if (bz < 2) {
        bf16* out = (bz == 0) ? qb : kb;
#pragma unroll
        for (int n = 0; n < 4; ++n) {
            const int gcol = n0 + wn * 64 + n * 16 + lr;
            const float bb = bias[gcol];
#pragma unroll
            for (int m = 0; m < 4; ++m)
#pragma unroll
                for (int j = 0; j < 4; ++j) {
                    const int grow = m0 + wm * 64 + m * 16 + kq * 4 + j;
                    out[(size_t)grow * EE + gcol] = (bf16)(acc[m][n][j] + bb);
                }
        }
    } else {
        // ---- transposed epilogue: acc -> LDS [256 e][128 s] -> vt[b][e][s]
        __syncthreads();   // kloop drained; LDS buffers dead
#pragma unroll
        for (int n = 0; n < 4; ++n) {
            const int gc = wn * 64 + n * 16 + lr;      // local e row 0..255
            const float bb = bias[n0 + gc];
#pragma unroll
            for (int m = 0; m < 4; ++m) {
                const int gr = wm * 64 + m * 16 + kq * 4;  // local s col
                union { unsigned short u[4]; uint2 v; } h;
#pragma unroll
                for (int j = 0; j < 4; ++j) {
                    union { bf16 b; unsigned short u; } cv;
                    cv.b = (bf16)(acc[m][n][j] + bb);
                    h.u[j] = cv.u;
                }
                char* p = lds + gc * 256 + (((gr >> 3) ^ (gc & 7)) << 4) + (gr & 7) * 2;
                *(uint2*)p = h.v;
            }
        }
        __syncthreads();
        const int r = tid >> 1, par = tid & 1;
        const int bb_ = m0 >> 11;          // batch index
        const int s0 = m0 & (SS - 1);      // seq offset within batch
        bf16* dst = vt + ((size_t)bb_ * EE + n0 + r) * SS + s0 + par * 64;
#pragma unroll
        for (int i = 0; i < 8; ++i) {
            const int c = par * 8 + i;
            const char* p = lds + r * 256 + ((c ^ (r & 7)) << 4);
            *(uint4*)&dst[i * 8] = *(const uint4*)p;
        }
    }
}

// ---------------------------------------------------------------------------
// K3: scores+exp [r14]: sc = exp(q.k/32 + mask) (UNNORMALIZED probs, bf16)
// and per-row partial sums -> part[16][B*S] fp32 (deterministic: one writer
// per slot; no atomics). Max-free softmax is safe: scores ~ N(0,1), max over
// 16.8M samples ~ 5.3 sigma -> exp <= ~200. pv divides by the row total.
// 256 thr, kloop32w. Grid (8,16,4) = 512 blocks.
// ---------------------------------------------------------------------------
__global__ __launch_bounds__(256, 2) void scores8(const bf16* __restrict__ qb,
                                                  const bf16* __restrict__ kb,
                                                  const float* __restrict__ mask,
                                                  bf16* __restrict__ sc,
                                                  float* __restrict__ part)
{
    extern __shared__ char lds[];
    int bx, by, bz; swz_block(bx, by, bz);
    const bf16* A  = qb + (size_t)bz * SS * EE;
    const bf16* Bm = kb + (size_t)bz * SS * EE;

    const int m0 = by * 128, n0 = bx * 256;
    const int tid = threadIdx.x;

    f32x4 acc[4][8];
#pragma unroll
    for (int m = 0; m < 4; ++m)
#pragma unroll
        for (int n = 0; n < 8; ++n) { acc[m][n][0] = 0.f; acc[m][n][1] = 0.f; acc[m][n][2] = 0.f; acc[m][n][3] = 0.f; }

    kloop32w(A, Bm, EE, EE, EE / 32, lds, m0, n0, tid, acc);

    const int lane = tid & 63, w = tid >> 6, wm = w >> 1, wn = w & 1;
    const int lr = lane & 15, kq = lane >> 4;
    const float* mrow = mask + (size_t)bz * SS * SS;
    bf16* out = sc + (size_t)bz * SS * SS;
    const float scale = 0.03125f;  // 1/sqrt(1024)

    float rp[4][4];
#pragma unroll
    for (int m = 0; m < 4; ++m)
#pragma unroll
        for (int j = 0; j < 4; ++j) rp[m][j] = 0.f;

#pragma unroll
    for (int m = 0; m < 4; ++m)
#pragma unroll
        for (int n = 0; n < 8; ++n)
#pragma unroll
            for (int j = 0; j < 4; ++j) {
                const int grow = m0 + wm * 64 + m * 16 + kq * 4 + j;
                const int gcol = n0 + wn * 128 + n * 16 + lr;
                const float v = acc[m][n][j] * scale + mrow[(size_t)grow * SS + gcol];
                const float e = __expf(v);
                out[(size_t)grow * SS + gcol] = (bf16)e;
                rp[m][j] += e;
            }

    // reduce over the 16-lane lr group (covers the wave's 128 cols)
#pragma unroll
    for (int m = 0; m < 4; ++m)
#pragma unroll
        for (int j = 0; j < 4; ++j) {
            float s = rp[m][j];
            s += __shfl_xor(s, 1);
            s += __shfl_xor(s, 2);
            s += __shfl_xor(s, 4);
            s += __shfl_xor(s, 8);
            rp[m][j] = s;
        }
    if (lr == 0) {
        float* pp = part + (size_t)(bx * 2 + wn) * (NB * SS) + (size_t)bz * SS + m0;
#pragma unroll
        for (int m = 0; m < 4; ++m)
#pragma unroll
            for (int j = 0; j < 4; ++j)
                pp[wm * 64 + m * 16 + kq * 4 + j] = rp[m][j];
    }
}

// ---------------------------------------------------------------------------
// K5: out = (P_unnorm @ V^T) * invs. M=2048, N=1024, K=2048 per batch.
// Prologue sums the 16 row partials (deterministic) -> invs[128] in LDS;
// epilogue scales the fp32 accumulator rows. kloop64, LDS64P, 256 blocks.
// ---------------------------------------------------------------------------
__global__ __launch_bounds__(512) void pv8(const bf16* __restrict__ sc,
                                           const bf16* __restrict__ vt,
                                           const float* __restrict__ part,
                                           float* __restrict__ outp)
{
    extern __shared__ char lds[];
    int bx, by, bz; swz_block(bx, by, bz);
    const bf16* A  = sc + (size_t)bz * SS * SS;   // [2048][2048] unnorm probs
    const bf16* Bm = vt + (size_t)bz * EE * SS;   // [1024][2048]

    const int m0 = by * 128, n0 = bx * 256;
    const int tid = threadIdx.x;

    // row scale table: invs[r] = 1 / sum_i part[i][row]
    float* invs = (float*)(lds + LDS64);
    if (tid < 128) {
        const size_t rowb = (size_t)bz * SS + m0 + tid;
        float s = 0.f;
#pragma unroll
        for (int i = 0; i < 16; ++i) s += part[(size_t)i * (NB * SS) + rowb];
        invs[tid] = 1.0f / s;
    }
    __syncthreads();

    f32x4 acc[4][4];
#pragma unroll
    for (int m = 0; m < 4; ++m)
#pragma unroll
        for (int n = 0; n < 4; ++n) { acc[m][n][0] = 0.f; acc[m][n][1] = 0.f; acc[m][n][2] = 0.f; acc[m][n][3] = 0.f; }

    kloop64(A, Bm, SS, SS, SS / 64, lds, m0, n0, tid, acc);

    const int lane = tid & 63, w = tid >> 6, wm = w >> 2, wn = w & 3;
    const int lr = lane & 15, kq = lane >> 4;
#pragma unroll
    for (int m = 0; m < 4; ++m)
#pragma unroll
        for (int j = 0; j < 4; ++j) {
            const int lrow = wm * 64 + m * 16 + kq * 4 + j;
            const float iv = invs[lrow];
#pragma unroll
            for (int n = 0; n < 4; ++n) {
                const int gcol = n0 + wn * 64 + n * 16 + lr;
                outp[((size_t)bz * SS + m0 + lrow) * EE + gcol] = acc[m][n][j] * iv;
            }
        }
}

// ---------------------------------------------------------------------------
// Host launcher
// Inputs: 0 query 1 key 2 value 3 attn_mask 4 Wq 5 bq 6 Wk 7 bk 8 Wv 9 bv
// WS: qb | kb | part | vt | sc | Wc. q/k/v consumed as fp32 directly.
// ---------------------------------------------------------------------------
extern "C" void kernel_launch(void* const* d_in, const int* in_sizes, int n_in,
                              void* d_out, int out_size, void* d_ws, size_t ws_size,
                              hipStream_t stream)
{
    const float* query = (const float*)d_in[0];
    const float* key_  = (const float*)d_in[1];
    const float* value = (const float*)d_in[2];
    const float* mask  = (const float*)d_in[3];
    const float* Wq = (const float*)d_in[4];
    const float* bq = (const float*)d_in[5];
    const float* Wk = (const float*)d_in[6];
    const float* bk = (const float*)d_in[7];
    const float* Wv = (const float*)d_in[8];
    const float* bv = (const float*)d_in[9];
    float* outp = (float*)d_out;

    char* ws = (char*)d_ws;
    const size_t QKV = (size_t)NB * SS * EE * 2;   // 16,777,216 B
    const size_t SCB = (size_t)NB * SS * SS * 2;   // 33,554,432 B
    const size_t WCB = (size_t)3 * EE * EE * 2;    //  6,291,456 B
    if (ws_size < 4 * QKV + SCB + WCB) return;

    bf16* qb = (bf16*)(ws);
    bf16* kb = (bf16*)(ws + QKV);
    float* part = (float*)(ws + 2 * QKV);          // 512 KB row partials
    bf16* vt = (bf16*)(ws + 3 * QKV);
    bf16* sc = (bf16*)(ws + 4 * QKV);
    bf16* Wc = (bf16*)(ws + 4 * QKV + SCB);

    (void)hipFuncSetAttribute((const void*)proj8,   hipFuncAttributeMaxDynamicSharedMemorySize, LDSA3);
    (void)hipFuncSetAttribute((const void*)scores8, hipFuncAttributeMaxDynamicSharedMemorySize, LDS3);
    (void)hipFuncSetAttribute((const void*)pv8,     hipFuncAttributeMaxDynamicSharedMemorySize, LDS64P);

    dim3 blk(256), blk5(512);
    cvt_w<<<dim3(512, 3), blk, 0, stream>>>(Wq, Wk, Wv, Wc);

    proj8<<<dim3(EE / 256, (NB * SS) / 128, 3), blk5, LDSA3, stream>>>(
        query, key_, value, Wc, bq, bk, bv, qb, kb, vt);
    scores8<<<dim3(SS / 256, SS / 128, NB), blk, LDS3, stream>>>(qb, kb, mask, sc, part);
    pv8<<<dim3(EE / 256, SS / 128, NB), blk5, LDS64P, stream>>>(sc, vt, part, outp);
}

// Round 16
// 180.887 us; speedup vs baseline: 1.0541x; 1.0541x over previous
//
#include <hip/hip_runtime.h>
#include <cstdint>
#include <cstddef>

typedef __bf16 bf16;
typedef __bf16 bf16x8 __attribute__((ext_vector_type(8)));
typedef float  f32x4  __attribute__((ext_vector_type(4)));

#define NB 4
#define SS 2048
#define EE 1024

// kloop32/kloop32w buffer: A-tile 128x32 bf16 (8 KB) + B-tile 256x32 (16 KB)
#define BUFB   24576
#define LDS3   (3 * BUFB)     // 73728 B -> 2 blocks/CU (proj, scores)
// kloop64 buffer: A-tile 128x64 (16 KB) + B-tile 256x64 (32 KB)
#define BUFB64 49152
#define LDS64  (3 * BUFB64)   // 147456 B -> 1 block/CU (pv)
#define LDS64P (LDS64 + 512)  // + invs[128] row-scale table (pv)

// ---------------------------------------------------------------------------
// Async global->LDS, 16 B/lane. LDS dest = wave-uniform base + lane*16
// (m104/m108); global src is per-lane (swizzle applied on the src side).
// ---------------------------------------------------------------------------
static __device__ __forceinline__ void glds16(const bf16* g, void* l)
{
    __builtin_amdgcn_global_load_lds(
        (const __attribute__((address_space(1))) unsigned int*)g,
        (__attribute__((address_space(3))) unsigned int*)l,
        16, 0, 0);
}

// Bijective XCD-aware swizzle (all grids here have nwg % 8 == 0).
static __device__ __forceinline__ void swz_block(int& bx, int& by, int& bz)
{
    const int nx = gridDim.x, ny = gridDim.y;
    const int nwg = nx * ny * gridDim.z;
    int lin = blockIdx.x + nx * (blockIdx.y + ny * blockIdx.z);
    const int per = nwg >> 3;
    lin = (lin & 7) * per + (lin >> 3);
    bz = lin / (nx * ny);
    const int r = lin - bz * nx * ny;
    by = r / nx;
    bx = r - by * nx;
}

// ---------------------------------------------------------------------------
// kloop32 [r7/r9, measured best for proj: 70.6 us, MfmaUtil 30%, 2 blk/CU]:
// BK=32, BM=128, BN=256, 512 thr = 8 waves (2M x 4N), per-wave 64x64.
// NBUF=3, depth-2 prefetch, boundary vmcnt(3) (T4: never drain in-loop),
// dummy-tail restage. Swizzle: physical_chunk = logical_chunk ^ ((row>>1)&3)
// -> frag reads 2-way (free). Staging inverse-swizzles the GLOBAL source.
// ---------------------------------------------------------------------------
static __device__ __forceinline__ void kloop32(
    const bf16* __restrict__ A, const bf16* __restrict__ Bm,
    int lda, int ldb, int nt, char* lds, int m0, int n0, int tid,
    f32x4 acc[4][4])
{
    constexpr int NBUF = 3;
    const int lane = tid & 63, w = tid >> 6;
    const int wm = w >> 2, wn = w & 3;
    const int lr = lane & 15, kq = lane >> 4;
    const int cb = ((kq ^ ((lr >> 1) & 3)) << 4);

    const int srow   = tid >> 2;
    const int chunkL = (tid & 3) ^ ((srow >> 1) & 3);
    const bf16* Asrc = A  + (size_t)(m0 + srow) * lda + chunkL * 8;
    const bf16* Bsrc = Bm + (size_t)(n0 + srow) * ldb + chunkL * 8;
    const int wofs = w << 10;

#pragma unroll
    for (int p = 0; p < NBUF - 1; ++p) {
        char* d = lds + p * BUFB + wofs;
        const int kt = p * 32;
        glds16(Asrc + kt,                     d);
        glds16(Bsrc + kt,                     d + 8192);
        glds16(Bsrc + (size_t)128 * ldb + kt, d + 16384);
    }
    asm volatile("s_waitcnt vmcnt(3)" ::: "memory");
    __builtin_amdgcn_sched_barrier(0);
    __builtin_amdgcn_s_barrier();
    __builtin_amdgcn_sched_barrier(0);

    int rb = 0, sb = NBUF - 1;
    for (int t = 0; t < nt; ++t) {
        char* la = lds + rb * BUFB;
        char* lb = la + 8192;
        const int ts = (t + NBUF - 1 < nt) ? t + NBUF - 1 : nt - 1; // dummy tail
        const int kt = ts * 32;
        char* d = lds + sb * BUFB + wofs;

        bf16x8 af[4], bg[4];
#pragma unroll
        for (int m = 0; m < 4; ++m)
            af[m] = *(const bf16x8*)(la + (wm * 64 + m * 16 + lr) * 64 + cb);
#pragma unroll
        for (int n = 0; n < 4; ++n)
            bg[n] = *(const bf16x8*)(lb + (wn * 64 + n * 16 + lr) * 64 + cb);

        glds16(Asrc + kt,                     d);
        glds16(Bsrc + kt,                     d + 8192);
        glds16(Bsrc + (size_t)128 * ldb + kt, d + 16384);

        __builtin_amdgcn_s_setprio(1);
#pragma unroll
        for (int m = 0; m < 4; ++m)
#pragma unroll
            for (int n = 0; n < 4; ++n)
                acc[m][n] = __builtin_amdgcn_mfma_f32_16x16x32_bf16(af[m], bg[n], acc[m][n], 0, 0, 0);
        __builtin_amdgcn_s_setprio(0);

        if (t < nt - 1) {
            asm volatile("s_waitcnt vmcnt(3)" ::: "memory");
            __builtin_amdgcn_sched_barrier(0);
            __builtin_amdgcn_s_barrier();
            __builtin_amdgcn_sched_barrier(0);
        }
        rb = (rb + 1 == NBUF) ? 0 : rb + 1;
        sb = (sb + 1 == NBUF) ? 0 : sb + 1;
    }
    asm volatile("s_waitcnt vmcnt(0)" ::: "memory");  // drain dummy-tail loads
}

// ---------------------------------------------------------------------------
// kloop32w [r12, measured best for scores]: BK=32, BM=128, BN=256,
// 256 thr = 4 waves (2M x 2N), per-wave 64x128. Same NBUF=3 / vmcnt(6)
// pipeline; 6 glds16/thread/tile (4 KB issues). Swizzle identical.
// ---------------------------------------------------------------------------
static __device__ __forceinline__ void kloop32w(
    const bf16* __restrict__ A, const bf16* __restrict__ Bm,
    int lda, int ldb, int nt, char* lds, int m0, int n0, int tid,
    f32x4 acc[4][8])
{
    constexpr int NBUF = 3;
    const int lane = tid & 63, w = tid >> 6;       // w 0..3
    const int wm = w >> 1, wn = w & 1;
    const int lr = lane & 15, kq = lane >> 4;
    const int cb = ((kq ^ ((lr >> 1) & 3)) << 4);

    const int srow   = tid >> 2;                   // 0..63
    const int chunkL = (tid & 3) ^ ((srow >> 1) & 3);
    const bf16* Asrc = A  + (size_t)(m0 + srow) * lda + chunkL * 8;
    const bf16* Bsrc = Bm + (size_t)(n0 + srow) * ldb + chunkL * 8;
    const int wofs = w << 10;                      // wave base within 4 KB issue

#pragma unroll
    for (int p = 0; p < NBUF - 1; ++p) {
        char* d = lds + p * BUFB + wofs;
        const int kt = p * 32;
        glds16(Asrc + kt,                      d);
        glds16(Asrc + (size_t)64  * lda + kt,  d + 4096);
        glds16(Bsrc + kt,                      d + 8192);
        glds16(Bsrc + (size_t)64  * ldb + kt,  d + 12288);
        glds16(Bsrc + (size_t)128 * ldb + kt,  d + 16384);
        glds16(Bsrc + (size_t)192 * ldb + kt,  d + 20480);
    }
    asm volatile("s_waitcnt vmcnt(6)" ::: "memory");
    __builtin_amdgcn_sched_barrier(0);
    __builtin_amdgcn_s_barrier();
    __builtin_amdgcn_sched_barrier(0);

    int rb = 0, sb = NBUF - 1;
    for (int t = 0; t < nt; ++t) {
        char* la = lds + rb * BUFB;
        char* lb = la + 8192;
        const int ts = (t + NBUF - 1 < nt) ? t + NBUF - 1 : nt - 1; // dummy tail
        const int kt = ts * 32;
        char* d = lds + sb * BUFB + wofs;

        bf16x8 af[4], bg[8];
#pragma unroll
        for (int m = 0; m < 4; ++m)
            af[m] = *(const bf16x8*)(la + (wm * 64 + m * 16 + lr) * 64 + cb);
#pragma unroll
        for (int n = 0; n < 8; ++n)
            bg[n] = *(const bf16x8*)(lb + (wn * 128 + n * 16 + lr) * 64 + cb);

        glds16(Asrc + kt,                      d);
        glds16(Asrc + (size_t)64  * lda + kt,  d + 4096);
        glds16(Bsrc + kt,                      d + 8192);
        glds16(Bsrc + (size_t)64  * ldb + kt,  d + 12288);
        glds16(Bsrc + (size_t)128 * ldb + kt,  d + 16384);
        glds16(Bsrc + (size_t)192 * ldb + kt,  d + 20480);

        __builtin_amdgcn_s_setprio(1);
#pragma unroll
        for (int m = 0; m < 4; ++m)
#pragma unroll
            for (int n = 0; n < 8; ++n)
                acc[m][n] = __builtin_amdgcn_mfma_f32_16x16x32_bf16(af[m], bg[n], acc[m][n], 0, 0, 0);
        __builtin_amdgcn_s_setprio(0);

        if (t < nt - 1) {
            asm volatile("s_waitcnt vmcnt(6)" ::: "memory");
            __builtin_amdgcn_sched_barrier(0);
            __builtin_amdgcn_s_barrier();
            __builtin_amdgcn_sched_barrier(0);
        }
        rb = (rb + 1 == NBUF) ? 0 : rb + 1;
        sb = (sb + 1 == NBUF) ? 0 : sb + 1;
    }
    asm volatile("s_waitcnt vmcnt(0)" ::: "memory");  // drain dummy-tail loads
}

// ---------------------------------------------------------------------------
// kloop64 [r3 verbatim; used by pv]: BK=64, BM=128, BN=256, NBUF=3 x 48 KB
// (1 block/CU), depth-2, boundary vmcnt(6), two k-slice phases per tile.
// Swizzle: chunk ^= (row&7) on 128-B rows (measured 0 conflicts).
// ---------------------------------------------------------------------------
static __device__ __forceinline__ void kloop64(
    const bf16* __restrict__ A, const bf16* __restrict__ Bm,
    int lda, int ldb, int nt, char* lds, int m0, int n0, int tid,
    f32x4 acc[4][4])
{
    const int lane = tid & 63, w = tid >> 6;
    const int wm = w >> 2, wn = w & 3;
    const int lr = lane & 15, kq = lane >> 4;
    const int axor = (lr & 7) << 4;

    const int srow   = tid >> 3;
    const int chunkL = (tid & 7) ^ (srow & 7);
    const bf16* Asrc = A  + (size_t)(m0 + srow) * lda + chunkL * 8;
    const bf16* Bsrc = Bm + (size_t)(n0 + srow) * ldb + chunkL * 8;
    const int wofs = w << 10;

#pragma unroll
    for (int p = 0; p < 2; ++p) {
        char* d = lds + p * BUFB64 + wofs;
        const int kt = p * 64;
        glds16(Asrc + kt,                        d);
        glds16(Asrc + (size_t)64 * lda + kt,     d + 8192);
        glds16(Bsrc + kt,                        d + 16384);
        glds16(Bsrc + (size_t)64 * ldb + kt,     d + 16384 + 8192);
        glds16(Bsrc + (size_t)128 * ldb + kt,    d + 16384 + 16384);
        glds16(Bsrc + (size_t)192 * ldb + kt,    d + 16384 + 24576);
    }
    asm volatile("s_waitcnt vmcnt(6)" ::: "memory");
    __builtin_amdgcn_sched_barrier(0);
    __builtin_amdgcn_s_barrier();
    __builtin_amdgcn_sched_barrier(0);

    for (int t = 0; t < nt; ++t) {
        char* la = lds + (t % 3) * BUFB64;
        char* lb = la + 16384;
        char* sa = lds + ((t + 2) % 3) * BUFB64;
        const bool st = (t + 2) < nt;
        const int kt = (t + 2) * 64;

        bf16x8 af[4], bg[4];
        {
            const int cbk = (kq * 16) ^ axor;
#pragma unroll
            for (int m = 0; m < 4; ++m)
                af[m] = *(const bf16x8*)(la + (wm * 64 + m * 16 + lr) * 128 + cbk);
#pragma unroll
            for (int n = 0; n < 4; ++n)
                bg[n] = *(const bf16x8*)(lb + (wn * 64 + n * 16 + lr) * 128 + cbk);
            if (st) {
                glds16(Asrc + kt,                    sa + wofs);
                glds16(Asrc + (size_t)64 * lda + kt, sa + 8192 + wofs);
                glds16(Bsrc + kt,                    sa + 16384 + wofs);
            }
            __builtin_amdgcn_s_setprio(1);
#pragma unroll
            for (int m = 0; m < 4; ++m)
#pragma unroll
                for (int n = 0; n < 4; ++n)
                    acc[m][n] = __builtin_amdgcn_mfma_f32_16x16x32_bf16(af[m], bg[n], acc[m][n], 0, 0, 0);
            __builtin_amdgcn_s_setprio(0);
        }
        {
            const int cbk = (64 + kq * 16) ^ axor;
#pragma unroll
            for (int m = 0; m < 4; ++m)
                af[m] = *(const bf16x8*)(la + (wm * 64 + m * 16 + lr) * 128 + cbk);
#pragma unroll
            for (int n = 0; n < 4; ++n)
                bg[n] = *(const bf16x8*)(lb + (wn * 64 + n * 16 + lr) * 128 + cbk);
            if (st) {
                glds16(Bsrc + (size_t)64 * ldb + kt,  sa + 16384 + 8192 + wofs);
                glds16(Bsrc + (size_t)128 * ldb + kt, sa + 16384 + 16384 + wofs);
                glds16(Bsrc + (size_t)192 * ldb + kt, sa + 16384 + 24576 + wofs);
            }
            __builtin_amdgcn_s_setprio(1);
#pragma unroll
            for (int m = 0; m < 4; ++m)
#pragma unroll
                for (int n = 0; n < 4; ++n)
                    acc[m][n] = __builtin_amdgcn_mfma_f32_16x16x32_bf16(af[m], bg[n], acc[m][n], 0, 0, 0);
            __builtin_amdgcn_s_setprio(0);
        }
        if (t < nt - 1) {
            if (st) { asm volatile("s_waitcnt vmcnt(6)" ::: "memory"); }
            else    { asm volatile("s_waitcnt vmcnt(0)" ::: "memory"); }
            __builtin_amdgcn_sched_barrier(0);
            __builtin_amdgcn_s_barrier();
            __builtin_amdgcn_sched_barrier(0);
        }
    }
}

// ---------------------------------------------------------------------------
// K0: fp32 -> bf16 convert, 8 elems/thread. One launch covers q/k/v
// (bx < 4096) and Wq/Wk/Wv (bx >= 4096); y selects tensor.
// ---------------------------------------------------------------------------
__global__ __launch_bounds__(256) void cvt_all(
    const float* __restrict__ q, const float* __restrict__ k, const float* __restrict__ v,
    const float* __restrict__ Wq, const float* __restrict__ Wk, const float* __restrict__ Wv,
    bf16* __restrict__ qc, bf16* __restrict__ kc, bf16* __restrict__ vc,
    bf16* __restrict__ Wc)
{
    const int y = blockIdx.y;
    const float* s; bf16* d; size_t i;
    if (blockIdx.x < 4096) {
        s = (y == 0) ? q : (y == 1) ? k : v;
        d = (y == 0) ? qc : (y == 1) ? kc : vc;
        i = ((size_t)blockIdx.x * 256 + threadIdx.x) * 8;
    } else {
        s = (y == 0) ? Wq : (y == 1) ? Wk : Wv;
        d = Wc + (size_t)y * EE * EE;
        i = ((size_t)(blockIdx.x - 4096) * 256 + threadIdx.x) * 8;
    }
    const float4 f0 = *(const float4*)(s + i);
    const float4 f1 = *(const float4*)(s + i + 4);
    bf16x8 h;
    h[0] = (bf16)f0.x; h[1] = (bf16)f0.y; h[2] = (bf16)f0.z; h[3] = (bf16)f0.w;
    h[4] = (bf16)f1.x; h[5] = (bf16)f1.y; h[6] = (bf16)f1.z; h[7] = (bf16)f1.w;
    *(bf16x8*)(d + i) = h;
}

// ---------------------------------------------------------------------------
// K1: fused QKV projection [r9/r11 — 512 thr, kloop32]. M=8192 (flat b*s),
// N=K=1024, z selects q/k/v. z<2: [s][e] bf16 write. z==2 (value): epilogue
// transposes via chunk-XOR LDS tile -> vt[b][e][s] (b=m0>>11, s0=m0&2047).
// C/D 16x16 layout: col = lane&15, row = (lane>>4)*4 + j  [m89/m91].
// ---------------------------------------------------------------------------
__global__ __launch_bounds__(512, 4) void proj8(
    const bf16* __restrict__ qc, const bf16* __restrict__ kc, const bf16* __restrict__ vc,
    const bf16* __restrict__ Wc,
    const float* __restrict__ bq, const float* __restrict__ bk, const float* __restrict__ bv,
    bf16* __restrict__ qb, bf16* __restrict__ kb, bf16* __restrict__ vt)
{
    extern __shared__ char lds[];
    int bx, by, bz; swz_block(bx, by, bz);
    const bf16* A; const float* bias;
    if (bz == 0)      { A = qc; bias = bq; }
    else if (bz == 1) { A = kc; bias = bk; }
    else              { A = vc; bias = bv; }
    const bf16* Bm = Wc + (size_t)bz * EE * EE;

    const int m0 = by * 128, n0 = bx * 256;
    const int tid = threadIdx.x;

    f32x4 acc[4][4];
#pragma unroll
    for (int m = 0; m < 4; ++m)
#pragma unroll
        for (int n = 0; n < 4; ++n) { acc[m][n][0] = 0.f; acc[m][n][1] = 0.f; acc[m][n][2] = 0.f; acc[m][n][3] = 0.f; }

    kloop32(A, Bm, EE, EE, EE / 32, lds, m0, n0, tid, acc);

    const int lane = tid & 63, w = tid >> 6, wm = w >> 2, wn = w & 3;
    const int lr = lane & 15, kq = lane >> 4;

    if (bz < 2) {
        bf16* out = (bz == 0) ? qb : kb;
#pragma unroll
        for (int n = 0; n < 4; ++n) {
            const int gcol = n0 + wn * 64 + n * 16 + lr;
            const float bb = bias[gcol];
#pragma unroll
            for (int m = 0; m < 4; ++m)
#pragma unroll
                for (int j = 0; j < 4; ++j) {
                    const int grow = m0 + wm * 64 + m * 16 + kq * 4 + j;
                    out[(size_t)grow * EE + gcol] = (bf16)(acc[m][n][j] + bb);
                }
        }
    } else {
        // ---- transposed epilogue: acc -> LDS [256 e][128 s] -> vt[b][e][s]
        __syncthreads();   // kloop32 drained; LDS buffers dead
#pragma unroll
        for (int n = 0; n < 4; ++n) {
            const int gc = wn * 64 + n * 16 + lr;      // local e row 0..255
            const float bb = bias[n0 + gc];
#pragma unroll
            for (int m = 0; m < 4; ++m) {
                const int gr = wm * 64 + m * 16 + kq * 4;  // local s col
                union { unsigned short u[4]; uint2 v; } h;
#pragma unroll
                for (int j = 0; j < 4; ++j) {
                    union { bf16 b; unsigned short u; } cv;
                    cv.b = (bf16)(acc[m][n][j] + bb);
                    h.u[j] = cv.u;
                }
                char* p = lds + gc * 256 + (((gr >> 3) ^ (gc & 7)) << 4) + (gr & 7) * 2;
                *(uint2*)p = h.v;
            }
        }
        __syncthreads();
        const int r = tid >> 1, par = tid & 1;
        const int bb_ = m0 >> 11;          // batch index
        const int s0 = m0 & (SS - 1);      // seq offset within batch
        bf16* dst = vt + ((size_t)bb_ * EE + n0 + r) * SS + s0 + par * 64;
#pragma unroll
        for (int i = 0; i < 8; ++i) {
            const int c = par * 8 + i;
            const char* p = lds + r * 256 + ((c ^ (r & 7)) << 4);
            *(uint4*)&dst[i * 8] = *(const uint4*)p;
        }
    }
}

// ---------------------------------------------------------------------------
// K3: scores+exp [r14]: sc = exp(q.k/32 + mask) (UNNORMALIZED probs, bf16)
// and per-row partial sums -> part[16][B*S] fp32 (deterministic: one writer
// per slot; no atomics). Max-free softmax is safe: scores ~ N(0,1), max over
// 16.8M samples ~ 5.3 sigma -> exp <= ~200. pv divides by the row total.
// 256 thr, kloop32w. Grid (8,16,4) = 512 blocks.
// ---------------------------------------------------------------------------
__global__ __launch_bounds__(256, 2) void scores8(const bf16* __restrict__ qb,
                                                  const bf16* __restrict__ kb,
                                                  const float* __restrict__ mask,
                                                  bf16* __restrict__ sc,
                                                  float* __restrict__ part)
{
    extern __shared__ char lds[];
    int bx, by, bz; swz_block(bx, by, bz);
    const bf16* A  = qb + (size_t)bz * SS * EE;
    const bf16* Bm = kb + (size_t)bz * SS * EE;

    const int m0 = by * 128, n0 = bx * 256;
    const int tid = threadIdx.x;

    f32x4 acc[4][8];
#pragma unroll
    for (int m = 0; m < 4; ++m)
#pragma unroll
        for (int n = 0; n < 8; ++n) { acc[m][n][0] = 0.f; acc[m][n][1] = 0.f; acc[m][n][2] = 0.f; acc[m][n][3] = 0.f; }

    kloop32w(A, Bm, EE, EE, EE / 32, lds, m0, n0, tid, acc);

    const int lane = tid & 63, w = tid >> 6, wm = w >> 1, wn = w & 1;
    const int lr = lane & 15, kq = lane >> 4;
    const float* mrow = mask + (size_t)bz * SS * SS;
    bf16* out = sc + (size_t)bz * SS * SS;
    const float scale = 0.03125f;  // 1/sqrt(1024)

    float rp[4][4];
#pragma unroll
    for (int m = 0; m < 4; ++m)
#pragma unroll
        for (int j = 0; j < 4; ++j) rp[m][j] = 0.f;

#pragma unroll
    for (int m = 0; m < 4; ++m)
#pragma unroll
        for (int n = 0; n < 8; ++n)
#pragma unroll
            for (int j = 0; j < 4; ++j) {
                const int grow = m0 + wm * 64 + m * 16 + kq * 4 + j;
                const int gcol = n0 + wn * 128 + n * 16 + lr;
                const float v = acc[m][n][j] * scale + mrow[(size_t)grow * SS + gcol];
                const float e = __expf(v);
                out[(size_t)grow * SS + gcol] = (bf16)e;
                rp[m][j] += e;
            }

    // reduce over the 16-lane lr group (covers the wave's 128 cols)
#pragma unroll
    for (int m = 0; m < 4; ++m)
#pragma unroll
        for (int j = 0; j < 4; ++j) {
            float s = rp[m][j];
            s += __shfl_xor(s, 1);
            s += __shfl_xor(s, 2);
            s += __shfl_xor(s, 4);
            s += __shfl_xor(s, 8);
            rp[m][j] = s;
        }
    if (lr == 0) {
        float* pp = part + (size_t)(bx * 2 + wn) * (NB * SS) + (size_t)bz * SS + m0;
#pragma unroll
        for (int m = 0; m < 4; ++m)
#pragma unroll
            for (int j = 0; j < 4; ++j)
                pp[wm * 64 + m * 16 + kq * 4 + j] = rp[m][j];
    }
}

// ---------------------------------------------------------------------------
// K5: out = (P_unnorm @ V^T) * invs. M=2048, N=1024, K=2048 per batch.
// Prologue sums the 16 row partials (deterministic) -> invs[128] in LDS;
// epilogue scales the fp32 accumulator rows. kloop64, LDS64P, 256 blocks.
// ---------------------------------------------------------------------------
__global__ __launch_bounds__(512) void pv8(const bf16* __restrict__ sc,
                                           const bf16* __restrict__ vt,
                                           const float* __restrict__ part,
                                           float* __restrict__ outp)
{
    extern __shared__ char lds[];
    int bx, by, bz; swz_block(bx, by, bz);
    const bf16* A  = sc + (size_t)bz * SS * SS;   // [2048][2048] unnorm probs
    const bf16* Bm = vt + (size_t)bz * EE * SS;   // [1024][2048]

    const int m0 = by * 128, n0 = bx * 256;
    const int tid = threadIdx.x;

    // row scale table: invs[r] = 1 / sum_i part[i][row]
    float* invs = (float*)(lds + LDS64);
    if (tid < 128) {
        const size_t rowb = (size_t)bz * SS + m0 + tid;
        float s = 0.f;
#pragma unroll
        for (int i = 0; i < 16; ++i) s += part[(size_t)i * (NB * SS) + rowb];
        invs[tid] = 1.0f / s;
    }
    __syncthreads();

    f32x4 acc[4][4];
#pragma unroll
    for (int m = 0; m < 4; ++m)
#pragma unroll
        for (int n = 0; n < 4; ++n) { acc[m][n][0] = 0.f; acc[m][n][1] = 0.f; acc[m][n][2] = 0.f; acc[m][n][3] = 0.f; }

    kloop64(A, Bm, SS, SS, SS / 64, lds, m0, n0, tid, acc);

    const int lane = tid & 63, w = tid >> 6, wm = w >> 2, wn = w & 3;
    const int lr = lane & 15, kq = lane >> 4;
#pragma unroll
    for (int m = 0; m < 4; ++m)
#pragma unroll
        for (int j = 0; j < 4; ++j) {
            const int lrow = wm * 64 + m * 16 + kq * 4 + j;
            const float iv = invs[lrow];
#pragma unroll
            for (int n = 0; n < 4; ++n) {
                const int gcol = n0 + wn * 64 + n * 16 + lr;
                outp[((size_t)bz * SS + m0 + lrow) * EE + gcol] = acc[m][n][j] * iv;
            }
        }
}

// ---------------------------------------------------------------------------
// Host launcher
// Inputs: 0 query 1 key 2 value 3 attn_mask 4 Wq 5 bq 6 Wk 7 bk 8 Wv 9 bv
// WS: qb | kb | (qc / part) | vt | sc | Wc.
// qc slot (ws+2QKV) is dead after proj; its first 512 KB becomes the
// row-partial buffer written by scores and read by pv (stream-ordered).
// ---------------------------------------------------------------------------
extern "C" void kernel_launch(void* const* d_in, const int* in_sizes, int n_in,
                              void* d_out, int out_size, void* d_ws, size_t ws_size,
                              hipStream_t stream)
{
    const float* query = (const float*)d_in[0];
    const float* key_  = (const float*)d_in[1];
    const float* value = (const float*)d_in[2];
    const float* mask  = (const float*)d_in[3];
    const float* Wq = (const float*)d_in[4];
    const float* bq = (const float*)d_in[5];
    const float* Wk = (const float*)d_in[6];
    const float* bk = (const float*)d_in[7];
    const float* Wv = (const float*)d_in[8];
    const float* bv = (const float*)d_in[9];
    float* outp = (float*)d_out;

    char* ws = (char*)d_ws;
    const size_t QKV = (size_t)NB * SS * EE * 2;   // 16,777,216 B
    const size_t SCB = (size_t)NB * SS * SS * 2;   // 33,554,432 B
    const size_t WCB = (size_t)3 * EE * EE * 2;    //  6,291,456 B
    if (ws_size < 4 * QKV + SCB + WCB) return;

    bf16* qb = (bf16*)(ws);
    bf16* kb = (bf16*)(ws + QKV);
    bf16* vt = (bf16*)(ws + 3 * QKV);
    bf16* sc = (bf16*)(ws + 4 * QKV);
    bf16* Wc = (bf16*)(ws + 4 * QKV + SCB);
    bf16* qc = (bf16*)(ws + 2 * QKV);    // dead after proj
    float* part = (float*)(ws + 2 * QKV);// reuses qc slot after proj (512 KB)
    bf16* kc = sc;                       // lifetime ends before scores
    bf16* vc = (bf16*)(ws + 5 * QKV);

    (void)hipFuncSetAttribute((const void*)proj8,   hipFuncAttributeMaxDynamicSharedMemorySize, LDS3);
    (void)hipFuncSetAttribute((const void*)scores8, hipFuncAttributeMaxDynamicSharedMemorySize, LDS3);
    (void)hipFuncSetAttribute((const void*)pv8,     hipFuncAttributeMaxDynamicSharedMemorySize, LDS64P);

    dim3 blk(256), blk5(512);
    cvt_all<<<dim3(4096 + 512, 3), blk, 0, stream>>>(
        query, key_, value, Wq, Wk, Wv, qc, kc, vc, Wc);

    proj8<<<dim3(EE / 256, (NB * SS) / 128, 3), blk5, LDS3, stream>>>(
        qc, kc, vc, Wc, bq, bk, bv, qb, kb, vt);
    scores8<<<dim3(SS / 256, SS / 128, NB), blk, LDS3, stream>>>(qb, kb, mask, sc, part);
    pv8<<<dim3(EE / 256, SS / 128, NB), blk5, LDS64P, stream>>>(sc, vt, part, outp);
}